// Round 1
// baseline (518.797 us; speedup 1.0000x reference)
//
#include <hip/hip_runtime.h>
#include <hip/hip_bf16.h>

// ---------------------------------------------------------------------------
// Fused causal MHA forward: x[B,T,C] fp32, w_qkv[3C,C] fp32, w_out[C,C] fp32
// B=4 T=2048 C=1024 H=16 hd=64.  All matmuls in bf16 MFMA, fp32 accumulate.
// Pipeline: convert->bf16 | GEMM qkv | flash-attn | GEMM out-proj (fp32 out).
// ---------------------------------------------------------------------------

typedef __attribute__((ext_vector_type(8))) short bf16x8;
typedef __attribute__((ext_vector_type(4))) float f32x4;

#define GLOBAL_AS __attribute__((address_space(1)))
#define LDS_AS __attribute__((address_space(3)))

__device__ __forceinline__ unsigned short f2b_rne(float f) {
  unsigned u = __float_as_uint(f);
  unsigned r = u + 0x7fffu + ((u >> 16) & 1u);
  return (unsigned short)(r >> 16);
}
__device__ __forceinline__ float b2f(unsigned short s) {
  return __uint_as_float(((unsigned)s) << 16);
}

__device__ __forceinline__ void gload_lds16(const void* g, void* l) {
  __builtin_amdgcn_global_load_lds((const GLOBAL_AS void*)g, (LDS_AS void*)l, 16, 0, 0);
}

// ---------------------------------------------------------------------------
// fp32 -> bf16 conversion (vectorized, grid-stride)
// ---------------------------------------------------------------------------
__global__ void f32_to_bf16_vec(const float* __restrict__ src,
                                unsigned short* __restrict__ dst, int n4) {
  int i = blockIdx.x * blockDim.x + threadIdx.x;
  int stride = gridDim.x * blockDim.x;
  for (; i < n4; i += stride) {
    float4 v = reinterpret_cast<const float4*>(src)[i];
    ushort4 o;
    o.x = f2b_rne(v.x); o.y = f2b_rne(v.y);
    o.z = f2b_rne(v.z); o.w = f2b_rne(v.w);
    reinterpret_cast<ushort4*>(dst)[i] = o;
  }
}

// ---------------------------------------------------------------------------
// NT GEMM: C[M,N] = A[M,K] * B[N,K]^T, bf16 in, fp32 acc.
// 128x128 tile, 4 waves (2x2), 4x4 16x16x32 fragments per wave, BK=32.
// Staging via global_load_lds width=16. OUT_BF16: store bf16 else fp32.
// ---------------------------------------------------------------------------
template <int OUT_BF16>
__global__ __launch_bounds__(256)
void gemm_nt(const unsigned short* __restrict__ A,
             const unsigned short* __restrict__ B,
             void* __restrict__ Cout, int M, int N, int K) {
  __shared__ __align__(16) unsigned short As[128][32];
  __shared__ __align__(16) unsigned short Bs[128][32];
  const int tid = threadIdx.x;
  const int w = tid >> 6, lane = tid & 63;
  const int l16 = lane & 15, lg = lane >> 4;
  const int wrow = (w >> 1) * 64, wcol = (w & 1) * 64;
  const int m0 = blockIdx.y * 128, n0 = blockIdx.x * 128;

  f32x4 acc[4][4] = {};

  auto stage = [&](int k0) {
    // wave w stages 16-row chunks {2w, 2w+1} of both tiles (1 KiB per load)
#pragma unroll
    for (int c2 = 0; c2 < 2; ++c2) {
      int c = 2 * w + c2;
      const unsigned short* ga =
          A + (size_t)(m0 + 16 * c + (lane >> 2)) * K + k0 + (lane & 3) * 8;
      gload_lds16(ga, &As[16 * c][0]);
      const unsigned short* gb =
          B + (size_t)(n0 + 16 * c + (lane >> 2)) * K + k0 + (lane & 3) * 8;
      gload_lds16(gb, &Bs[16 * c][0]);
    }
  };

  stage(0);
  __syncthreads();
  const int nk = K >> 5;
  for (int ks = 0; ks < nk; ++ks) {
    bf16x8 af[4], bfr[4];
#pragma unroll
    for (int mi = 0; mi < 4; ++mi)
      af[mi] = *(const bf16x8*)&As[wrow + mi * 16 + l16][lg * 8];
#pragma unroll
    for (int ni = 0; ni < 4; ++ni)
      bfr[ni] = *(const bf16x8*)&Bs[wcol + ni * 16 + l16][lg * 8];
    __syncthreads();
    if (ks + 1 < nk) stage((ks + 1) * 32);
#pragma unroll
    for (int mi = 0; mi < 4; ++mi)
#pragma unroll
      for (int ni = 0; ni < 4; ++ni)
        acc[mi][ni] = __builtin_amdgcn_mfma_f32_16x16x32_bf16(
            af[mi], bfr[ni], acc[mi][ni], 0, 0, 0);
    __syncthreads();
  }

  // epilogue: D lane mapping row=(lg*4+j), col=l16 per 16x16 tile
#pragma unroll
  for (int mi = 0; mi < 4; ++mi) {
#pragma unroll
    for (int ni = 0; ni < 4; ++ni) {
#pragma unroll
      for (int j = 0; j < 4; ++j) {
        int row = m0 + wrow + mi * 16 + lg * 4 + j;
        int col = n0 + wcol + ni * 16 + l16;
        if (OUT_BF16) {
          ((unsigned short*)Cout)[(size_t)row * N + col] =
              f2b_rne(acc[mi][ni][j]);
        } else {
          ((float*)Cout)[(size_t)row * N + col] = acc[mi][ni][j];
        }
      }
    }
  }
}

// ---------------------------------------------------------------------------
// Flash attention fwd, causal. qkv[B*T, 3072] bf16 (q|k|v per row),
// out[B*T, 1024] bf16. Block: 4 waves, 64 q-rows (16 per wave), KV tile 32.
// Per wave: S = Q K^T (2 n-tiles x 2 k-steps), online softmax (fp32),
// P via LDS round-trip, O += P V (V transposed in LDS).
// ---------------------------------------------------------------------------
__global__ __launch_bounds__(256)
void attn_fwd(const unsigned short* __restrict__ qkv,
              unsigned short* __restrict__ out) {
  const int T = 2048, C3 = 3072;
  __shared__ __align__(16) unsigned short Ks[32][72];   // K tile, row-major, +8 pad
  __shared__ __align__(16) unsigned short Vt[64][40];   // V tile transposed [d][kv]
  __shared__ __align__(16) unsigned short Ps[4][16][32];// per-wave P tile

  const int tid = threadIdx.x, w = tid >> 6, lane = tid & 63;
  const int l16 = lane & 15, lg = lane >> 4;
  const int qt = blockIdx.x, bh = blockIdx.y;
  const int b = bh >> 4, h = bh & 15;
  const int q0 = qt * 64, qw = q0 + w * 16;
  const size_t rowbase = (size_t)b * T * C3;
  const int hoff = h * 64;

  // Q fragments in registers: qf[f] covers d in [32f, 32f+32)
  bf16x8 qf[2];
  {
    const unsigned short* qp =
        qkv + rowbase + (size_t)(qw + l16) * C3 + hoff + lg * 8;
    qf[0] = *(const bf16x8*)qp;
    qf[1] = *(const bf16x8*)(qp + 32);
  }

  f32x4 oacc[4] = {};
  float m_i[4], l_i[4];
#pragma unroll
  for (int j = 0; j < 4; ++j) { m_i[j] = -1e30f; l_i[j] = 0.f; }

  const int ntiles = qt * 2 + 2;
  for (int t = 0; t < ntiles; ++t) {
    const int kv0 = t * 32;
    __syncthreads();  // all waves done reading previous K/V
    {
      int r = tid >> 3, cc = (tid & 7) * 8;
      const unsigned short* kp =
          qkv + rowbase + (size_t)(kv0 + r) * C3 + 1024 + hoff + cc;
      *(bf16x8*)&Ks[r][cc] = *(const bf16x8*)kp;
      bf16x8 vv = *(const bf16x8*)(kp + 1024);
#pragma unroll
      for (int i = 0; i < 8; ++i) Vt[cc + i][r] = (unsigned short)vv[i];
    }
    __syncthreads();  // staging visible

    if (kv0 <= qw + 15) {  // wave-uniform causal skip
      // S = Q K^T : sacc[nt] covers kv cols nt*16+l16, rows lg*4+j
      f32x4 sacc[2] = {};
#pragma unroll
      for (int ds = 0; ds < 2; ++ds) {
        bf16x8 kf0 = *(const bf16x8*)&Ks[l16][ds * 32 + lg * 8];
        bf16x8 kf1 = *(const bf16x8*)&Ks[16 + l16][ds * 32 + lg * 8];
        sacc[0] = __builtin_amdgcn_mfma_f32_16x16x32_bf16(qf[ds], kf0, sacc[0], 0, 0, 0);
        sacc[1] = __builtin_amdgcn_mfma_f32_16x16x32_bf16(qf[ds], kf1, sacc[1], 0, 0, 0);
      }
      // online softmax per row j (row group = 16 consecutive lanes)
#pragma unroll
      for (int j = 0; j < 4; ++j) {
        float s0 = sacc[0][j] * 0.125f;
        float s1 = sacc[1][j] * 0.125f;
        int q_abs = qw + lg * 4 + j;
        if (kv0 + l16 > q_abs) s0 = -1e30f;
        if (kv0 + 16 + l16 > q_abs) s1 = -1e30f;
        float tm = fmaxf(s0, s1);
#pragma unroll
        for (int off = 1; off < 16; off <<= 1)
          tm = fmaxf(tm, __shfl_xor(tm, off));
        float mnew = fmaxf(m_i[j], tm);
        float corr = __expf(m_i[j] - mnew);
        unsigned short pb0 = f2b_rne(__expf(s0 - mnew));
        unsigned short pb1 = f2b_rne(__expf(s1 - mnew));
        Ps[w][lg * 4 + j][l16] = pb0;
        Ps[w][lg * 4 + j][16 + l16] = pb1;
        float ts = b2f(pb0) + b2f(pb1);
#pragma unroll
        for (int off = 1; off < 16; off <<= 1) ts += __shfl_xor(ts, off);
        l_i[j] = l_i[j] * corr + ts;
        m_i[j] = mnew;
#pragma unroll
        for (int dt = 0; dt < 4; ++dt) oacc[dt][j] *= corr;
      }
      // O += P V  (A-frag from Ps, B-frag from Vt, both contiguous b128)
      bf16x8 pa = *(const bf16x8*)&Ps[w][l16][lg * 8];
#pragma unroll
      for (int dt = 0; dt < 4; ++dt) {
        bf16x8 bv = *(const bf16x8*)&Vt[dt * 16 + l16][lg * 8];
        oacc[dt] = __builtin_amdgcn_mfma_f32_16x16x32_bf16(pa, bv, oacc[dt], 0, 0, 0);
      }
    }
  }

  // normalize and store bf16
#pragma unroll
  for (int dt = 0; dt < 4; ++dt) {
#pragma unroll
    for (int j = 0; j < 4; ++j) {
      float v = oacc[dt][j] / l_i[j];
      out[(size_t)(b * T + qw + lg * 4 + j) * 1024 + hoff + dt * 16 + l16] =
          f2b_rne(v);
    }
  }
}

// ---------------------------------------------------------------------------
extern "C" void kernel_launch(void* const* d_in, const int* in_sizes, int n_in,
                              void* d_out, int out_size, void* d_ws,
                              size_t ws_size, hipStream_t stream) {
  const float* x = (const float*)d_in[0];      // [4,2048,1024]
  const float* w_qkv = (const float*)d_in[1];  // [3072,1024]
  const float* w_out = (const float*)d_in[2];  // [1024,1024]
  float* out = (float*)d_out;                  // [4,2048,1024] fp32

  const int M = 8192, C = 1024, C3 = 3072;

  unsigned short* xb = (unsigned short*)d_ws;           // M*C
  unsigned short* wqkvb = xb + (size_t)M * C;           // C3*C
  unsigned short* woutb = wqkvb + (size_t)C3 * C;       // C*C
  unsigned short* qkv = woutb + (size_t)C * C;          // M*C3
  unsigned short* attno = qkv + (size_t)M * C3;         // M*C

  // convert inputs to bf16
  f32_to_bf16_vec<<<1024, 256, 0, stream>>>(x, xb, M * C / 4);
  f32_to_bf16_vec<<<512, 256, 0, stream>>>(w_qkv, wqkvb, C3 * C / 4);
  f32_to_bf16_vec<<<256, 256, 0, stream>>>(w_out, woutb, C * C / 4);

  // qkv = x @ w_qkv^T  -> bf16 [M, 3072]
  gemm_nt<1><<<dim3(C3 / 128, M / 128), 256, 0, stream>>>(xb, wqkvb, qkv, M, C3, C);

  // flash attention -> bf16 [M, 1024]
  attn_fwd<<<dim3(2048 / 64, 64), 256, 0, stream>>>(qkv, attno);

  // out = attno @ w_out^T -> fp32
  gemm_nt<0><<<dim3(C / 128, M / 128), 256, 0, stream>>>(attno, woutb, out, M, C, C);
}

// Round 3
// 355.850 us; speedup vs baseline: 1.4579x; 1.4579x over previous
//
#include <hip/hip_runtime.h>
#include <hip/hip_bf16.h>

// ---------------------------------------------------------------------------
// Fused causal MHA forward: x[B,T,C] fp32, w_qkv[3C,C] fp32, w_out[C,C] fp32
// B=4 T=2048 C=1024 H=16 hd=64.  All matmuls in bf16 MFMA, fp32 accumulate.
// Pipeline: convert->bf16 | GEMM qkv | flash-attn | GEMM out-proj (fp32 out).
// ---------------------------------------------------------------------------

typedef __attribute__((ext_vector_type(8))) short bf16x8;
typedef __attribute__((ext_vector_type(4))) float f32x4;

#define GLOBAL_AS __attribute__((address_space(1)))
#define LDS_AS __attribute__((address_space(3)))

__device__ __forceinline__ unsigned short f2b_rne(float f) {
  unsigned u = __float_as_uint(f);
  unsigned r = u + 0x7fffu + ((u >> 16) & 1u);
  return (unsigned short)(r >> 16);
}
__device__ __forceinline__ float b2f(unsigned short s) {
  return __uint_as_float(((unsigned)s) << 16);
}

__device__ __forceinline__ void gload_lds16(const void* g, void* l) {
  __builtin_amdgcn_global_load_lds((const GLOBAL_AS void*)g, (LDS_AS void*)l, 16, 0, 0);
}

// ---------------------------------------------------------------------------
// fp32 -> bf16 conversion (vectorized, grid-stride)
// ---------------------------------------------------------------------------
__global__ void f32_to_bf16_vec(const float* __restrict__ src,
                                unsigned short* __restrict__ dst, int n4) {
  int i = blockIdx.x * blockDim.x + threadIdx.x;
  int stride = gridDim.x * blockDim.x;
  for (; i < n4; i += stride) {
    float4 v = reinterpret_cast<const float4*>(src)[i];
    ushort4 o;
    o.x = f2b_rne(v.x); o.y = f2b_rne(v.y);
    o.z = f2b_rne(v.z); o.w = f2b_rne(v.w);
    reinterpret_cast<ushort4*>(dst)[i] = o;
  }
}

// ---------------------------------------------------------------------------
// NT GEMM: C[M,N] = A[M,K] * B[N,K]^T, bf16 in, fp32 acc.
// 128x128 tile, 4 waves (2x2), 4x4 16x16x32 fragments per wave, BK=32.
// ---------------------------------------------------------------------------
template <int OUT_BF16>
__global__ __launch_bounds__(256)
void gemm_nt(const unsigned short* __restrict__ A,
             const unsigned short* __restrict__ B,
             void* __restrict__ Cout, int M, int N, int K) {
  __shared__ __align__(16) unsigned short As[128][32];
  __shared__ __align__(16) unsigned short Bs[128][32];
  const int tid = threadIdx.x;
  const int w = tid >> 6, lane = tid & 63;
  const int l16 = lane & 15, lg = lane >> 4;
  const int wrow = (w >> 1) * 64, wcol = (w & 1) * 64;
  const int m0 = blockIdx.y * 128, n0 = blockIdx.x * 128;

  f32x4 acc[4][4] = {};

  auto stage = [&](int k0) {
#pragma unroll
    for (int c2 = 0; c2 < 2; ++c2) {
      int c = 2 * w + c2;
      const unsigned short* ga =
          A + (size_t)(m0 + 16 * c + (lane >> 2)) * K + k0 + (lane & 3) * 8;
      gload_lds16(ga, &As[16 * c][0]);
      const unsigned short* gb =
          B + (size_t)(n0 + 16 * c + (lane >> 2)) * K + k0 + (lane & 3) * 8;
      gload_lds16(gb, &Bs[16 * c][0]);
    }
  };

  stage(0);
  __syncthreads();
  const int nk = K >> 5;
  for (int ks = 0; ks < nk; ++ks) {
    bf16x8 af[4], bfr[4];
#pragma unroll
    for (int mi = 0; mi < 4; ++mi)
      af[mi] = *(const bf16x8*)&As[wrow + mi * 16 + l16][lg * 8];
#pragma unroll
    for (int ni = 0; ni < 4; ++ni)
      bfr[ni] = *(const bf16x8*)&Bs[wcol + ni * 16 + l16][lg * 8];
    __syncthreads();
    if (ks + 1 < nk) stage((ks + 1) * 32);
#pragma unroll
    for (int mi = 0; mi < 4; ++mi)
#pragma unroll
      for (int ni = 0; ni < 4; ++ni)
        acc[mi][ni] = __builtin_amdgcn_mfma_f32_16x16x32_bf16(
            af[mi], bfr[ni], acc[mi][ni], 0, 0, 0);
    __syncthreads();
  }

#pragma unroll
  for (int mi = 0; mi < 4; ++mi) {
#pragma unroll
    for (int ni = 0; ni < 4; ++ni) {
#pragma unroll
      for (int j = 0; j < 4; ++j) {
        int row = m0 + wrow + mi * 16 + lg * 4 + j;
        int col = n0 + wcol + ni * 16 + l16;
        if (OUT_BF16) {
          ((unsigned short*)Cout)[(size_t)row * N + col] =
              f2b_rne(acc[mi][ni][j]);
        } else {
          ((float*)Cout)[(size_t)row * N + col] = acc[mi][ni][j];
        }
      }
    }
  }
}

// ---------------------------------------------------------------------------
// Flash attention fwd, causal. qkv[B*T, 3072] bf16 (q|k|v), out[B*T,1024] bf16.
// Block: 4 waves, 128 q-rows (32/wave = 2 m-frags), KV tile 64.
// K staged via global_load_lds with XOR-swizzled SOURCE (conflict-free reads).
// V transpose-staged with XOR block swizzle (conflict-free scatter writes).
// Row sums via MFMA with constant ones B-fragment (no shfl sum tree).
// ---------------------------------------------------------------------------
__global__ __launch_bounds__(256)
void attn_fwd(const unsigned short* __restrict__ qkv,
              unsigned short* __restrict__ out) {
  const int T = 2048, C3 = 3072;
  __shared__ __align__(16) unsigned short Ks[64][64];    // block-swizzled
  __shared__ __align__(16) unsigned short Vt[64][64];    // [d][kv], swizzled
  __shared__ __align__(16) unsigned short Ps[4][32][68]; // per-wave P

  const int tid = threadIdx.x, w = tid >> 6, lane = tid & 63;
  const int l16 = lane & 15, lg = lane >> 4;
  const int qt = 15 - blockIdx.x;  // heavy blocks first
  const int bh = blockIdx.y;
  const int b = bh >> 4, h = bh & 15;
  const int q0 = qt * 128, qw = q0 + w * 32;
  const size_t rowbase = (size_t)b * T * C3;
  const int hoff = h * 64;

  // Q fragments: qf[mi][ks] covers rows qw+mi*16+l16, d in [32ks,32ks+32)
  bf16x8 qf[2][2];
#pragma unroll
  for (int mi = 0; mi < 2; ++mi) {
    const unsigned short* qp =
        qkv + rowbase + (size_t)(qw + mi * 16 + l16) * C3 + hoff + lg * 8;
    qf[mi][0] = *(const bf16x8*)qp;
    qf[mi][1] = *(const bf16x8*)(qp + 32);
  }

  bf16x8 onesf;
#pragma unroll
  for (int i = 0; i < 8; ++i) onesf[i] = (short)0x3f80;  // bf16 1.0

  f32x4 oacc[2][4] = {};
  f32x4 psum[2] = {};
  float m_i[2][4];
#pragma unroll
  for (int mi = 0; mi < 2; ++mi)
#pragma unroll
    for (int j = 0; j < 4; ++j) m_i[mi][j] = -1e30f;

  const int ntiles = qt * 2 + 2;
  for (int t = 0; t < ntiles; ++t) {
    const int kv0 = t * 64;
    __syncthreads();  // everyone done reading previous K/V
    // ---- stage K: 8 chunks of 8 rows, gload_lds with swizzled source ----
#pragma unroll
    for (int p = 0; p < 2; ++p) {
      int chunk = w * 2 + p;
      int row = chunk * 8 + (lane >> 3);
      int blk = (lane & 7) ^ (lane >> 3);  // slot lane&7 holds block slot^(row&7)
      gload_lds16(qkv + rowbase + (size_t)(kv0 + row) * C3 + 1024 + hoff + blk * 8,
                  &Ks[chunk * 8][0]);
    }
    // ---- stage V transposed with swizzle: Vt[d][(g^((d>>3)&7))*8 + (r&7)] ----
#pragma unroll
    for (int p = 0; p < 2; ++p) {
      int r = p * 32 + (tid >> 3);
      int c = (tid & 7) * 8;
      bf16x8 vv = *(const bf16x8*)(qkv + rowbase + (size_t)(kv0 + r) * C3 +
                                   2048 + hoff + c);
      int g = r >> 3;
#pragma unroll
      for (int i = 0; i < 8; ++i) {
        int d = c + i;
        int gp = g ^ ((d >> 3) & 7);
        Vt[d][gp * 8 + (r & 7)] = (unsigned short)vv[i];
      }
    }
    __syncthreads();  // staging visible

    if (kv0 <= qw) {  // wave-uniform causal participation
      // ---- S = Q K^T : sacc[mi][ni] rows lg*4+j(+16mi), cols ni*16+l16 ----
      f32x4 sacc[2][4] = {};
#pragma unroll
      for (int ks = 0; ks < 2; ++ks) {
#pragma unroll
        for (int ni = 0; ni < 4; ++ni) {
          int row = ni * 16 + l16;
          int slot = (ks * 4 + lg) ^ (row & 7);
          bf16x8 kf = *(const bf16x8*)&Ks[row][slot * 8];
          sacc[0][ni] = __builtin_amdgcn_mfma_f32_16x16x32_bf16(
              qf[0][ks], kf, sacc[0][ni], 0, 0, 0);
          sacc[1][ni] = __builtin_amdgcn_mfma_f32_16x16x32_bf16(
              qf[1][ks], kf, sacc[1][ni], 0, 0, 0);
        }
      }
      const bool need_mask = (kv0 + 64 > qw);
      // ---- online softmax (max tree only; sums via MFMA ones column) ----
#pragma unroll
      for (int mi = 0; mi < 2; ++mi) {
#pragma unroll
        for (int j = 0; j < 4; ++j) {
          float s[4];
#pragma unroll
          for (int ni = 0; ni < 4; ++ni) s[ni] = sacc[mi][ni][j] * 0.125f;
          if (need_mask) {
            int q_abs = qw + mi * 16 + lg * 4 + j;
#pragma unroll
            for (int ni = 0; ni < 4; ++ni)
              if (kv0 + ni * 16 + l16 > q_abs) s[ni] = -1e30f;
          }
          float tm = fmaxf(fmaxf(s[0], s[1]), fmaxf(s[2], s[3]));
#pragma unroll
          for (int off = 1; off < 16; off <<= 1)
            tm = fmaxf(tm, __shfl_xor(tm, off));
          float mnew = fmaxf(m_i[mi][j], tm);
          float corr = __expf(m_i[mi][j] - mnew);
          m_i[mi][j] = mnew;
          int row = mi * 16 + lg * 4 + j;
#pragma unroll
          for (int ni = 0; ni < 4; ++ni)
            Ps[w][row][ni * 16 + l16] = f2b_rne(__expf(s[ni] - mnew));
          psum[mi][j] *= corr;
#pragma unroll
          for (int ni = 0; ni < 4; ++ni) oacc[mi][ni][j] *= corr;
        }
      }
      // ---- O += P V ; rowsum += P * ones ----
#pragma unroll
      for (int ks = 0; ks < 2; ++ks) {
        bf16x8 pa0 = *(const bf16x8*)&Ps[w][l16][ks * 32 + lg * 8];
        bf16x8 pa1 = *(const bf16x8*)&Ps[w][16 + l16][ks * 32 + lg * 8];
        psum[0] = __builtin_amdgcn_mfma_f32_16x16x32_bf16(pa0, onesf, psum[0], 0, 0, 0);
        psum[1] = __builtin_amdgcn_mfma_f32_16x16x32_bf16(pa1, onesf, psum[1], 0, 0, 0);
#pragma unroll
        for (int ni = 0; ni < 4; ++ni) {
          int d = ni * 16 + l16;
          int slot = (ks * 4 + lg) ^ ((d >> 3) & 7);
          bf16x8 bv = *(const bf16x8*)&Vt[d][slot * 8];
          oacc[0][ni] = __builtin_amdgcn_mfma_f32_16x16x32_bf16(pa0, bv, oacc[0][ni], 0, 0, 0);
          oacc[1][ni] = __builtin_amdgcn_mfma_f32_16x16x32_bf16(pa1, bv, oacc[1][ni], 0, 0, 0);
        }
      }
    }
  }

  // ---- normalize and store bf16 ----
#pragma unroll
  for (int mi = 0; mi < 2; ++mi) {
#pragma unroll
    for (int ni = 0; ni < 4; ++ni) {
#pragma unroll
      for (int j = 0; j < 4; ++j) {
        float v = oacc[mi][ni][j] / psum[mi][j];
        out[(size_t)(b * T + qw + mi * 16 + lg * 4 + j) * 1024 + hoff +
            ni * 16 + l16] = f2b_rne(v);
      }
    }
  }
}

// ---------------------------------------------------------------------------
extern "C" void kernel_launch(void* const* d_in, const int* in_sizes, int n_in,
                              void* d_out, int out_size, void* d_ws,
                              size_t ws_size, hipStream_t stream) {
  const float* x = (const float*)d_in[0];      // [4,2048,1024]
  const float* w_qkv = (const float*)d_in[1];  // [3072,1024]
  const float* w_out = (const float*)d_in[2];  // [1024,1024]
  float* out = (float*)d_out;                  // [4,2048,1024] fp32

  const int M = 8192, C = 1024, C3 = 3072;

  unsigned short* xb = (unsigned short*)d_ws;           // M*C
  unsigned short* wqkvb = xb + (size_t)M * C;           // C3*C
  unsigned short* woutb = wqkvb + (size_t)C3 * C;       // C*C
  unsigned short* qkv = woutb + (size_t)C * C;          // M*C3
  unsigned short* attno = qkv + (size_t)M * C3;         // M*C

  f32_to_bf16_vec<<<1024, 256, 0, stream>>>(x, xb, M * C / 4);
  f32_to_bf16_vec<<<512, 256, 0, stream>>>(w_qkv, wqkvb, C3 * C / 4);
  f32_to_bf16_vec<<<256, 256, 0, stream>>>(w_out, woutb, C * C / 4);

  gemm_nt<1><<<dim3(C3 / 128, M / 128), 256, 0, stream>>>(xb, wqkvb, qkv, M, C3, C);

  attn_fwd<<<dim3(2048 / 128, 64), 256, 0, stream>>>(qkv, attno);

  gemm_nt<0><<<dim3(C / 128, M / 128), 256, 0, stream>>>(attno, woutb, out, M, C, C);
}

// Round 4
// 241.384 us; speedup vs baseline: 2.1493x; 1.4742x over previous
//
#include <hip/hip_runtime.h>
#include <hip/hip_bf16.h>

// ---------------------------------------------------------------------------
// Fused causal MHA forward: x[B,T,C] fp32, w_qkv[3C,C] fp32, w_out[C,C] fp32
// B=4 T=2048 C=1024 H=16 hd=64.  All matmuls in bf16 MFMA, fp32 accumulate.
// Pipeline: convert->bf16 | GEMM qkv | flash-attn | GEMM out-proj (fp32 out).
// ---------------------------------------------------------------------------

typedef __attribute__((ext_vector_type(8))) short bf16x8;
typedef __attribute__((ext_vector_type(4))) float f32x4;
typedef __attribute__((ext_vector_type(16))) float f32x16;

#define GLOBAL_AS __attribute__((address_space(1)))
#define LDS_AS __attribute__((address_space(3)))

__device__ __forceinline__ unsigned short f2b_rne(float f) {
  unsigned u = __float_as_uint(f);
  unsigned r = u + 0x7fffu + ((u >> 16) & 1u);
  return (unsigned short)(r >> 16);
}

__device__ __forceinline__ unsigned cvt_pk_bf16(float lo, float hi) {
  unsigned r;
  asm("v_cvt_pk_bf16_f32 %0, %1, %2" : "=v"(r) : "v"(lo), "v"(hi));
  return r;
}

__device__ __forceinline__ void gload_lds16(const void* g, void* l) {
  __builtin_amdgcn_global_load_lds((const GLOBAL_AS void*)g, (LDS_AS void*)l, 16, 0, 0);
}

// ---------------------------------------------------------------------------
// fp32 -> bf16 conversion (vectorized, grid-stride)
// ---------------------------------------------------------------------------
__global__ void f32_to_bf16_vec(const float* __restrict__ src,
                                unsigned short* __restrict__ dst, int n4) {
  int i = blockIdx.x * blockDim.x + threadIdx.x;
  int stride = gridDim.x * blockDim.x;
  for (; i < n4; i += stride) {
    float4 v = reinterpret_cast<const float4*>(src)[i];
    ushort4 o;
    o.x = f2b_rne(v.x); o.y = f2b_rne(v.y);
    o.z = f2b_rne(v.z); o.w = f2b_rne(v.w);
    reinterpret_cast<ushort4*>(dst)[i] = o;
  }
}

// ---------------------------------------------------------------------------
// NT GEMM: C[M,N] = A[M,K] * B[N,K]^T, bf16 in, fp32 acc. (unchanged)
// ---------------------------------------------------------------------------
template <int OUT_BF16>
__global__ __launch_bounds__(256)
void gemm_nt(const unsigned short* __restrict__ A,
             const unsigned short* __restrict__ B,
             void* __restrict__ Cout, int M, int N, int K) {
  __shared__ __align__(16) unsigned short As[128][32];
  __shared__ __align__(16) unsigned short Bs[128][32];
  const int tid = threadIdx.x;
  const int w = tid >> 6, lane = tid & 63;
  const int l16 = lane & 15, lg = lane >> 4;
  const int wrow = (w >> 1) * 64, wcol = (w & 1) * 64;
  const int m0 = blockIdx.y * 128, n0 = blockIdx.x * 128;

  f32x4 acc[4][4] = {};

  auto stage = [&](int k0) {
#pragma unroll
    for (int c2 = 0; c2 < 2; ++c2) {
      int c = 2 * w + c2;
      const unsigned short* ga =
          A + (size_t)(m0 + 16 * c + (lane >> 2)) * K + k0 + (lane & 3) * 8;
      gload_lds16(ga, &As[16 * c][0]);
      const unsigned short* gb =
          B + (size_t)(n0 + 16 * c + (lane >> 2)) * K + k0 + (lane & 3) * 8;
      gload_lds16(gb, &Bs[16 * c][0]);
    }
  };

  stage(0);
  __syncthreads();
  const int nk = K >> 5;
  for (int ks = 0; ks < nk; ++ks) {
    bf16x8 af[4], bfr[4];
#pragma unroll
    for (int mi = 0; mi < 4; ++mi)
      af[mi] = *(const bf16x8*)&As[wrow + mi * 16 + l16][lg * 8];
#pragma unroll
    for (int ni = 0; ni < 4; ++ni)
      bfr[ni] = *(const bf16x8*)&Bs[wcol + ni * 16 + l16][lg * 8];
    __syncthreads();
    if (ks + 1 < nk) stage((ks + 1) * 32);
#pragma unroll
    for (int mi = 0; mi < 4; ++mi)
#pragma unroll
      for (int ni = 0; ni < 4; ++ni)
        acc[mi][ni] = __builtin_amdgcn_mfma_f32_16x16x32_bf16(
            af[mi], bfr[ni], acc[mi][ni], 0, 0, 0);
    __syncthreads();
  }

#pragma unroll
  for (int mi = 0; mi < 4; ++mi) {
#pragma unroll
    for (int ni = 0; ni < 4; ++ni) {
#pragma unroll
      for (int j = 0; j < 4; ++j) {
        int row = m0 + wrow + mi * 16 + lg * 4 + j;
        int col = n0 + wcol + ni * 16 + l16;
        if (OUT_BF16) {
          ((unsigned short*)Cout)[(size_t)row * N + col] =
              f2b_rne(acc[mi][ni][j]);
        } else {
          ((float*)Cout)[(size_t)row * N + col] = acc[mi][ni][j];
        }
      }
    }
  }
}

// ---------------------------------------------------------------------------
// Flash attention fwd, causal; swapped-QK^T 32x32 structure.
// Block: 4 waves x 32 q-rows = 128 q. KV tile 64.
// S^T = mfma_32x32x16(K, Q): lane holds P column for q = lane&31 (kv rows
// split with partner lane lane^32). Softmax fully in-register: 1 shfl for
// max, 1 for sum. P -> bf16 via v_cvt_pk + shfl exchange -> PV A-frags in
// registers (no LDS round-trip). Defer-max rescale (THR=16 raw units) with
// per-wave LDS broadcast on the rare rescale.
// ---------------------------------------------------------------------------
__global__ __launch_bounds__(256)
void attn_fwd(const unsigned short* __restrict__ qkv,
              unsigned short* __restrict__ out) {
  const int T = 2048, C3 = 3072;
  __shared__ __align__(16) unsigned short Ks[64][64];  // block-swizzled
  __shared__ __align__(16) unsigned short Vt[64][64];  // [d][kv], swizzled
  __shared__ float Bc[4][32];                          // per-wave broadcast

  const int tid = threadIdx.x, w = tid >> 6, lane = tid & 63;
  const int l31 = lane & 31, h = lane >> 5;
  const int qt = 15 - blockIdx.x;  // heavy blocks first
  const int bh = blockIdx.y;
  const int b = bh >> 4, hed = bh & 15;
  const int q0 = qt * 128, qw = q0 + w * 32;
  const size_t rowbase = (size_t)b * T * C3;
  const int hoff = hed * 64;

  // Q as B-operand frags: qf[s] = Q[qw + l31][hoff + 16s + 8h .. +8)
  bf16x8 qf[4];
  {
    const unsigned short* qp =
        qkv + rowbase + (size_t)(qw + l31) * C3 + hoff + h * 8;
#pragma unroll
    for (int s = 0; s < 4; ++s) qf[s] = *(const bf16x8*)(qp + 16 * s);
  }

  f32x16 oacc[2] = {};  // O: col d = 32dt + l31, rows q spread over regs
  float m_r = -1e30f, sum = 0.f;

  const int ntiles = qt * 2 + 2;
  for (int t = 0; t < ntiles; ++t) {
    const int kv0 = t * 64;
    __syncthreads();
    // ---- stage K via gload_lds, source pre-swizzled ----
#pragma unroll
    for (int p = 0; p < 2; ++p) {
      int chunk = w * 2 + p;
      int row = chunk * 8 + (lane >> 3);
      int blk = (lane & 7) ^ (lane >> 3);
      gload_lds16(
          qkv + rowbase + (size_t)(kv0 + row) * C3 + 1024 + hoff + blk * 8,
          &Ks[chunk * 8][0]);
    }
    // ---- stage V transposed, swizzled: Vt[d][(g^((d>>3)&7))*8 + (r&7)] ----
#pragma unroll
    for (int p = 0; p < 2; ++p) {
      int r = p * 32 + (tid >> 3);
      int c = (tid & 7) * 8;
      bf16x8 vv = *(const bf16x8*)(qkv + rowbase + (size_t)(kv0 + r) * C3 +
                                   2048 + hoff + c);
      int g = r >> 3;
#pragma unroll
      for (int i = 0; i < 8; ++i) {
        int d = c + i;
        Vt[d][((g ^ ((d >> 3) & 7)) * 8) + (r & 7)] = (unsigned short)vv[i];
      }
    }
    __syncthreads();

    if (kv0 <= qw) {  // wave-uniform causal participation
      // ---- S^T = K Q^T : sacc[kt] rows kv = 32kt + (r&3)+8(r>>2)+4h,
      //      col q = l31 ----
      f32x16 sacc[2] = {};
#pragma unroll
      for (int s = 0; s < 4; ++s) {
#pragma unroll
        for (int kt = 0; kt < 2; ++kt) {
          int row = kt * 32 + l31;
          int blk = (2 * s + h) ^ (row & 7);
          bf16x8 kf = *(const bf16x8*)&Ks[row][blk * 8];
          sacc[kt] = __builtin_amdgcn_mfma_f32_32x32x16_bf16(kf, qf[s],
                                                             sacc[kt], 0, 0, 0);
        }
      }
      // ---- causal mask (single diagonal tile per wave) ----
      if (kv0 + 64 > qw) {
        int q_abs = qw + l31;
#pragma unroll
        for (int kt = 0; kt < 2; ++kt)
#pragma unroll
          for (int r = 0; r < 16; ++r) {
            int kv_abs = kv0 + kt * 32 + (r & 3) + 8 * (r >> 2) + 4 * h;
            if (kv_abs > q_abs) sacc[kt][r] = -1e30f;
          }
      }
      // ---- tile max (in-lane tree + one partner shfl) ----
      float tm = sacc[0][0];
#pragma unroll
      for (int r = 1; r < 16; ++r) tm = fmaxf(tm, sacc[0][r]);
#pragma unroll
      for (int r = 0; r < 16; ++r) tm = fmaxf(tm, sacc[1][r]);
      tm = fmaxf(tm, __shfl_xor(tm, 32));
      if (t == 0) {
        m_r = tm;
      } else if (!__all(tm <= m_r + 16.0f)) {
        // rare rescale: broadcast corr[q] to O-layout via per-wave LDS
        float mnew = fmaxf(m_r, tm);
        float corr = __expf((m_r - mnew) * 0.125f);
        sum *= corr;
        if (h == 0) Bc[w][l31] = corr;
        m_r = mnew;
        asm volatile("s_waitcnt lgkmcnt(0)" ::: "memory");
#pragma unroll
        for (int r = 0; r < 16; ++r) {
          float cr = Bc[w][(r & 3) + 8 * (r >> 2) + 4 * h];
          oacc[0][r] *= cr;
          oacc[1][r] *= cr;
        }
      }
      // ---- P = exp(0.125(s - m)), in-register; accumulate sum ----
      float m8 = m_r * 0.125f;
      float sl = 0.f;
#pragma unroll
      for (int kt = 0; kt < 2; ++kt)
#pragma unroll
        for (int r = 0; r < 16; ++r) {
          float p = __expf(fmaf(sacc[kt][r], 0.125f, -m8));
          sacc[kt][r] = p;
          sl += p;
        }
      sum += sl + __shfl_xor(sl, 32);
      // ---- pack P pairs to bf16: pk[kt*8 + r/2] = (row 2e, row 2e+1) ----
      unsigned pk[16];
#pragma unroll
      for (int kt = 0; kt < 2; ++kt)
#pragma unroll
        for (int r = 0; r < 16; r += 2)
          pk[kt * 8 + (r >> 1)] = cvt_pk_bf16(sacc[kt][r], sacc[kt][r + 1]);
      // ---- PV: assemble A-frags (P rows q=l31, kv step 16sg) in regs ----
#pragma unroll
      for (int sg = 0; sg < 4; ++sg) {
        const int kt = sg >> 1, s = sg & 1;
        const int base = kt * 8 + 4 * s;
        unsigned ra = (unsigned)__shfl_xor((int)pk[base], 32);
        unsigned rb = (unsigned)__shfl_xor((int)pk[base + 1], 32);
        unsigned rc = (unsigned)__shfl_xor((int)pk[base + 2], 32);
        unsigned rd = (unsigned)__shfl_xor((int)pk[base + 3], 32);
        union { unsigned u[4]; bf16x8 v; } A;
        A.u[0] = h ? rc : pk[base];
        A.u[1] = h ? rd : pk[base + 1];
        A.u[2] = h ? pk[base + 2] : ra;
        A.u[3] = h ? pk[base + 3] : rb;
#pragma unroll
        for (int dt = 0; dt < 2; ++dt) {
          int d = dt * 32 + l31;
          int blk = (2 * sg + h) ^ ((d >> 3) & 7);
          bf16x8 vf = *(const bf16x8*)&Vt[d][blk * 8];
          oacc[dt] = __builtin_amdgcn_mfma_f32_32x32x16_bf16(A.v, vf,
                                                             oacc[dt], 0, 0, 0);
        }
      }
    }
  }

  // ---- epilogue: broadcast 1/sum[q] to O-layout, store bf16 ----
  if (h == 0) Bc[w][l31] = 1.0f / sum;
  asm volatile("s_waitcnt lgkmcnt(0)" ::: "memory");
#pragma unroll
  for (int r = 0; r < 16; ++r) {
    int ql = (r & 3) + 8 * (r >> 2) + 4 * h;
    float inv = Bc[w][ql];
    int q_abs = qw + ql;
#pragma unroll
    for (int dt = 0; dt < 2; ++dt) {
      out[(size_t)(b * T + q_abs) * 1024 + hoff + dt * 32 + l31] =
          f2b_rne(oacc[dt][r] * inv);
    }
  }
}

// ---------------------------------------------------------------------------
extern "C" void kernel_launch(void* const* d_in, const int* in_sizes, int n_in,
                              void* d_out, int out_size, void* d_ws,
                              size_t ws_size, hipStream_t stream) {
  const float* x = (const float*)d_in[0];      // [4,2048,1024]
  const float* w_qkv = (const float*)d_in[1];  // [3072,1024]
  const float* w_out = (const float*)d_in[2];  // [1024,1024]
  float* out = (float*)d_out;                  // [4,2048,1024] fp32

  const int M = 8192, C = 1024, C3 = 3072;

  unsigned short* xb = (unsigned short*)d_ws;           // M*C
  unsigned short* wqkvb = xb + (size_t)M * C;           // C3*C
  unsigned short* woutb = wqkvb + (size_t)C3 * C;       // C*C
  unsigned short* qkv = woutb + (size_t)C * C;          // M*C3
  unsigned short* attno = qkv + (size_t)M * C3;         // M*C

  f32_to_bf16_vec<<<1024, 256, 0, stream>>>(x, xb, M * C / 4);
  f32_to_bf16_vec<<<512, 256, 0, stream>>>(w_qkv, wqkvb, C3 * C / 4);
  f32_to_bf16_vec<<<256, 256, 0, stream>>>(w_out, woutb, C * C / 4);

  gemm_nt<1><<<dim3(C3 / 128, M / 128), 256, 0, stream>>>(xb, wqkvb, qkv, M, C3, C);

  attn_fwd<<<dim3(2048 / 128, 64), 256, 0, stream>>>(qkv, attno);

  gemm_nt<0><<<dim3(C / 128, M / 128), 256, 0, stream>>>(attno, woutb, out, M, C, C);
}

// Round 5
// 229.041 us; speedup vs baseline: 2.2651x; 1.0539x over previous
//
#include <hip/hip_runtime.h>
#include <hip/hip_bf16.h>

// ---------------------------------------------------------------------------
// Fused causal MHA forward: x[B,T,C] fp32, w_qkv[3C,C] fp32, w_out[C,C] fp32
// B=4 T=2048 C=1024 H=16 hd=64.  All matmuls in bf16 MFMA, fp32 accumulate.
// Pipeline: convert->bf16 | GEMM qkv | flash-attn | GEMM out-proj (fp32 out).
// ---------------------------------------------------------------------------

typedef __attribute__((ext_vector_type(8))) short bf16x8;
typedef __attribute__((ext_vector_type(4))) float f32x4;
typedef __attribute__((ext_vector_type(16))) float f32x16;

#define GLOBAL_AS __attribute__((address_space(1)))
#define LDS_AS __attribute__((address_space(3)))

__device__ __forceinline__ unsigned short f2b_rne(float f) {
  unsigned u = __float_as_uint(f);
  unsigned r = u + 0x7fffu + ((u >> 16) & 1u);
  return (unsigned short)(r >> 16);
}

__device__ __forceinline__ unsigned cvt_pk_bf16(float lo, float hi) {
  unsigned r;
  asm("v_cvt_pk_bf16_f32 %0, %1, %2" : "=v"(r) : "v"(lo), "v"(hi));
  return r;
}

__device__ __forceinline__ void gload_lds16(const void* g, void* l) {
  __builtin_amdgcn_global_load_lds((const GLOBAL_AS void*)g, (LDS_AS void*)l, 16, 0, 0);
}

// ---------------------------------------------------------------------------
// fp32 -> bf16 conversion (vectorized, grid-stride)
// ---------------------------------------------------------------------------
__global__ void f32_to_bf16_vec(const float* __restrict__ src,
                                unsigned short* __restrict__ dst, int n4) {
  int i = blockIdx.x * blockDim.x + threadIdx.x;
  int stride = gridDim.x * blockDim.x;
  for (; i < n4; i += stride) {
    float4 v = reinterpret_cast<const float4*>(src)[i];
    ushort4 o;
    o.x = f2b_rne(v.x); o.y = f2b_rne(v.y);
    o.z = f2b_rne(v.z); o.w = f2b_rne(v.w);
    reinterpret_cast<ushort4*>(dst)[i] = o;
  }
}

// ---------------------------------------------------------------------------
// NT GEMM: C[M,N] = A[M,K] * B[N,K]^T, bf16 in, fp32 acc. (unchanged)
// ---------------------------------------------------------------------------
template <int OUT_BF16>
__global__ __launch_bounds__(256)
void gemm_nt(const unsigned short* __restrict__ A,
             const unsigned short* __restrict__ B,
             void* __restrict__ Cout, int M, int N, int K) {
  __shared__ __align__(16) unsigned short As[128][32];
  __shared__ __align__(16) unsigned short Bs[128][32];
  const int tid = threadIdx.x;
  const int w = tid >> 6, lane = tid & 63;
  const int l16 = lane & 15, lg = lane >> 4;
  const int wrow = (w >> 1) * 64, wcol = (w & 1) * 64;
  const int m0 = blockIdx.y * 128, n0 = blockIdx.x * 128;

  f32x4 acc[4][4] = {};

  auto stage = [&](int k0) {
#pragma unroll
    for (int c2 = 0; c2 < 2; ++c2) {
      int c = 2 * w + c2;
      const unsigned short* ga =
          A + (size_t)(m0 + 16 * c + (lane >> 2)) * K + k0 + (lane & 3) * 8;
      gload_lds16(ga, &As[16 * c][0]);
      const unsigned short* gb =
          B + (size_t)(n0 + 16 * c + (lane >> 2)) * K + k0 + (lane & 3) * 8;
      gload_lds16(gb, &Bs[16 * c][0]);
    }
  };

  stage(0);
  __syncthreads();
  const int nk = K >> 5;
  for (int ks = 0; ks < nk; ++ks) {
    bf16x8 af[4], bfr[4];
#pragma unroll
    for (int mi = 0; mi < 4; ++mi)
      af[mi] = *(const bf16x8*)&As[wrow + mi * 16 + l16][lg * 8];
#pragma unroll
    for (int ni = 0; ni < 4; ++ni)
      bfr[ni] = *(const bf16x8*)&Bs[wcol + ni * 16 + l16][lg * 8];
    __syncthreads();
    if (ks + 1 < nk) stage((ks + 1) * 32);
#pragma unroll
    for (int mi = 0; mi < 4; ++mi)
#pragma unroll
      for (int ni = 0; ni < 4; ++ni)
        acc[mi][ni] = __builtin_amdgcn_mfma_f32_16x16x32_bf16(
            af[mi], bfr[ni], acc[mi][ni], 0, 0, 0);
    __syncthreads();
  }

#pragma unroll
  for (int mi = 0; mi < 4; ++mi) {
#pragma unroll
    for (int ni = 0; ni < 4; ++ni) {
#pragma unroll
      for (int j = 0; j < 4; ++j) {
        int row = m0 + wrow + mi * 16 + lg * 4 + j;
        int col = n0 + wcol + ni * 16 + l16;
        if (OUT_BF16) {
          ((unsigned short*)Cout)[(size_t)row * N + col] =
              f2b_rne(acc[mi][ni][j]);
        } else {
          ((float*)Cout)[(size_t)row * N + col] = acc[mi][ni][j];
        }
      }
    }
  }
}

// ---------------------------------------------------------------------------
// Flash attention fwd, causal; swapped-QK^T 32x32 structure.
// Block: 4 waves x 32 q-rows = 128 q. KV tile 64, double-buffered.
// Single barrier per tile: issue t+1 loads -> compute on t -> V ds_write
// (drain) -> barrier.  XCD-swizzled 1D grid for KV L2 locality.
// ---------------------------------------------------------------------------
__global__ __launch_bounds__(256)
void attn_fwd(const unsigned short* __restrict__ qkv,
              unsigned short* __restrict__ out) {
  const int T = 2048, C3 = 3072;
  __shared__ __align__(16) unsigned short Ks[2][64][64];  // block-swizzled
  __shared__ __align__(16) unsigned short Vt[2][64][64];  // [d][kv], swizzled
  __shared__ float Bc[4][32];                             // per-wave broadcast

  const int tid = threadIdx.x, w = tid >> 6, lane = tid & 63;
  const int l31 = lane & 31, h = lane >> 5;
  // XCD swizzle: 1024 blocks = 8 XCDs x 128. XCD k gets bh in [8k, 8k+8),
  // qt descending (heavy first) within each bh.
  const int wgid = (blockIdx.x & 7) * 128 + (blockIdx.x >> 3);
  const int qt = 15 - (wgid & 15);
  const int bh = wgid >> 4;
  const int b = bh >> 4, hed = bh & 15;
  const int q0 = qt * 128, qw = q0 + w * 32;
  const size_t rowbase = (size_t)b * T * C3;
  const int hoff = hed * 64;

  auto stageK = [&](int t, int buf) {
#pragma unroll
    for (int p = 0; p < 2; ++p) {
      int chunk = w * 2 + p;
      int row = chunk * 8 + (lane >> 3);
      int blk = (lane & 7) ^ (lane >> 3);
      gload_lds16(
          qkv + rowbase + (size_t)(t * 64 + row) * C3 + 1024 + hoff + blk * 8,
          &Ks[buf][chunk * 8][0]);
    }
  };
  auto loadV = [&](int t, bf16x8* vv) {
#pragma unroll
    for (int p = 0; p < 2; ++p) {
      int r = p * 32 + (tid >> 3);
      vv[p] = *(const bf16x8*)(qkv + rowbase + (size_t)(t * 64 + r) * C3 +
                               2048 + hoff + (tid & 7) * 8);
    }
  };
  auto writeV = [&](bf16x8* vv, int buf) {
#pragma unroll
    for (int p = 0; p < 2; ++p) {
      int r = p * 32 + (tid >> 3);
      int c = (tid & 7) * 8;
      int g = r >> 3;
#pragma unroll
      for (int i = 0; i < 8; ++i) {
        int d = c + i;
        Vt[buf][d][((g ^ ((d >> 3) & 7)) * 8) + (r & 7)] =
            (unsigned short)vv[p][i];
      }
    }
  };

  // Q as B-operand frags: qf[s] = Q[qw + l31][hoff + 16s + 8h .. +8)
  bf16x8 qf[4];
  {
    const unsigned short* qp =
        qkv + rowbase + (size_t)(qw + l31) * C3 + hoff + h * 8;
#pragma unroll
    for (int s = 0; s < 4; ++s) qf[s] = *(const bf16x8*)(qp + 16 * s);
  }

  f32x16 oacc[2] = {};  // O: col d = 32dt + l31, rows q spread over regs
  float m_r = -1e30f, sum = 0.f;

  // prologue: stage tile 0 into buffer 0
  {
    bf16x8 vv[2];
    stageK(0, 0);
    loadV(0, vv);
    writeV(vv, 0);
  }
  __syncthreads();

  int cur = 0;
  const int ntiles = qt * 2 + 2;
  for (int t = 0; t < ntiles; ++t) {
    const int kv0 = t * 64;
    const bool have_next = (t + 1 < ntiles);
    bf16x8 vv[2];
    if (have_next) {        // issue next-tile loads early (fly under compute)
      stageK(t + 1, cur ^ 1);
      loadV(t + 1, vv);
    }

    if (kv0 <= qw) {  // wave-uniform causal participation
      // ---- S^T = K Q^T : sacc[kt] rows kv = 32kt + (r&3)+8(r>>2)+4h ----
      f32x16 sacc[2] = {};
#pragma unroll
      for (int s = 0; s < 4; ++s) {
#pragma unroll
        for (int kt = 0; kt < 2; ++kt) {
          int row = kt * 32 + l31;
          int blk = (2 * s + h) ^ (row & 7);
          bf16x8 kf = *(const bf16x8*)&Ks[cur][row][blk * 8];
          sacc[kt] = __builtin_amdgcn_mfma_f32_32x32x16_bf16(kf, qf[s],
                                                             sacc[kt], 0, 0, 0);
        }
      }
      // ---- causal mask (diagonal tiles only) ----
      if (kv0 + 64 > qw) {
        int q_abs = qw + l31;
#pragma unroll
        for (int kt = 0; kt < 2; ++kt)
#pragma unroll
          for (int r = 0; r < 16; ++r) {
            int kv_abs = kv0 + kt * 32 + (r & 3) + 8 * (r >> 2) + 4 * h;
            if (kv_abs > q_abs) sacc[kt][r] = -1e30f;
          }
      }
      // ---- tile max (in-lane tree + one partner shfl) ----
      float tm = sacc[0][0];
#pragma unroll
      for (int r = 1; r < 16; ++r) tm = fmaxf(tm, sacc[0][r]);
#pragma unroll
      for (int r = 0; r < 16; ++r) tm = fmaxf(tm, sacc[1][r]);
      tm = fmaxf(tm, __shfl_xor(tm, 32));
      if (t == 0) {
        m_r = tm;
      } else if (!__all(tm <= m_r + 16.0f)) {
        float mnew = fmaxf(m_r, tm);
        float corr = __expf((m_r - mnew) * 0.125f);
        sum *= corr;
        if (h == 0) Bc[w][l31] = corr;
        m_r = mnew;
        asm volatile("s_waitcnt lgkmcnt(0)" ::: "memory");
#pragma unroll
        for (int r = 0; r < 16; ++r) {
          float cr = Bc[w][(r & 3) + 8 * (r >> 2) + 4 * h];
          oacc[0][r] *= cr;
          oacc[1][r] *= cr;
        }
      }
      // ---- P = exp(0.125(s - m)), in-register; accumulate sum ----
      float m8 = m_r * 0.125f;
      float sl = 0.f;
#pragma unroll
      for (int kt = 0; kt < 2; ++kt)
#pragma unroll
        for (int r = 0; r < 16; ++r) {
          float p = __expf(fmaf(sacc[kt][r], 0.125f, -m8));
          sacc[kt][r] = p;
          sl += p;
        }
      sum += sl + __shfl_xor(sl, 32);
      // ---- pack P pairs to bf16 ----
      unsigned pk[16];
#pragma unroll
      for (int kt = 0; kt < 2; ++kt)
#pragma unroll
        for (int r = 0; r < 16; r += 2)
          pk[kt * 8 + (r >> 1)] = cvt_pk_bf16(sacc[kt][r], sacc[kt][r + 1]);
      // ---- PV: assemble A-frags in regs, accumulate ----
#pragma unroll
      for (int sg = 0; sg < 4; ++sg) {
        const int kt = sg >> 1, s = sg & 1;
        const int base = kt * 8 + 4 * s;
        unsigned ra = (unsigned)__shfl_xor((int)pk[base], 32);
        unsigned rb = (unsigned)__shfl_xor((int)pk[base + 1], 32);
        unsigned rc = (unsigned)__shfl_xor((int)pk[base + 2], 32);
        unsigned rd = (unsigned)__shfl_xor((int)pk[base + 3], 32);
        union { unsigned u[4]; bf16x8 v; } A;
        A.u[0] = h ? rc : pk[base];
        A.u[1] = h ? rd : pk[base + 1];
        A.u[2] = h ? pk[base + 2] : ra;
        A.u[3] = h ? pk[base + 3] : rb;
#pragma unroll
        for (int dt = 0; dt < 2; ++dt) {
          int d = dt * 32 + l31;
          int blk = (2 * sg + h) ^ ((d >> 3) & 7);
          bf16x8 vf = *(const bf16x8*)&Vt[cur][d][blk * 8];
          oacc[dt] = __builtin_amdgcn_mfma_f32_32x32x16_bf16(A.v, vf,
                                                             oacc[dt], 0, 0, 0);
        }
      }
    }

    if (have_next) writeV(vv, cur ^ 1);  // drain V loads after compute
    __syncthreads();                     // next tile ready; prev reads done
    cur ^= 1;
  }

  // ---- epilogue: broadcast 1/sum[q] to O-layout, store bf16 ----
  if (h == 0) Bc[w][l31] = 1.0f / sum;
  asm volatile("s_waitcnt lgkmcnt(0)" ::: "memory");
#pragma unroll
  for (int r = 0; r < 16; ++r) {
    int ql = (r & 3) + 8 * (r >> 2) + 4 * h;
    float inv = Bc[w][ql];
    int q_abs = qw + ql;
#pragma unroll
    for (int dt = 0; dt < 2; ++dt) {
      out[(size_t)(b * T + q_abs) * 1024 + hoff + dt * 32 + l31] =
          f2b_rne(oacc[dt][r] * inv);
    }
  }
}

// ---------------------------------------------------------------------------
extern "C" void kernel_launch(void* const* d_in, const int* in_sizes, int n_in,
                              void* d_out, int out_size, void* d_ws,
                              size_t ws_size, hipStream_t stream) {
  const float* x = (const float*)d_in[0];      // [4,2048,1024]
  const float* w_qkv = (const float*)d_in[1];  // [3072,1024]
  const float* w_out = (const float*)d_in[2];  // [1024,1024]
  float* out = (float*)d_out;                  // [4,2048,1024] fp32

  const int M = 8192, C = 1024, C3 = 3072;

  unsigned short* xb = (unsigned short*)d_ws;           // M*C
  unsigned short* wqkvb = xb + (size_t)M * C;           // C3*C
  unsigned short* woutb = wqkvb + (size_t)C3 * C;       // C*C
  unsigned short* qkv = woutb + (size_t)C * C;          // M*C3
  unsigned short* attno = qkv + (size_t)M * C3;         // M*C

  f32_to_bf16_vec<<<1024, 256, 0, stream>>>(x, xb, M * C / 4);
  f32_to_bf16_vec<<<512, 256, 0, stream>>>(w_qkv, wqkvb, C3 * C / 4);
  f32_to_bf16_vec<<<256, 256, 0, stream>>>(w_out, woutb, C * C / 4);

  gemm_nt<1><<<dim3(C3 / 128, M / 128), 256, 0, stream>>>(xb, wqkvb, qkv, M, C3, C);

  attn_fwd<<<1024, 256, 0, stream>>>(qkv, attno);

  gemm_nt<0><<<dim3(C / 128, M / 128), 256, 0, stream>>>(attno, woutb, out, M, C, C);
}